// Round 4
// baseline (670.588 us; speedup 1.0000x reference)
//
#include <hip/hip_runtime.h>

// z_{t+1} = z_t @ K, T=256, B=256, D=512. out[b,t,d] = (z0 @ K^{t+1})[b,d], fp32.
//
// 3 dispatches total:
//   1) prep: pack K (4 fragment-packed forms), split z0, zero grid barrier.
//   2) ladder_kernel: ALL 9 sequential levels (K powers bf16x3 + W_j = z0@K^{16j})
//      fused into one kernel, 256 co-resident WGs, device-scope grid barriers.
//   3) gemm_out: out[16j+i] = W_j @ K^{i+1}, plain bf16, XCD-local (i,j,n) remap.
//
// Fragment-packed layout: 1KB chunks = what 64 lanes of one 16x16x32 MFMA frag
// read (elem = chunk*512 + lane*8 + j). A-frags load direct from global
// (dwordx4); B panels are contiguous -> gll16 staging, conflict-free LDS.
// Slot (u16): [Apk-hi | Apk-lo | Bpk-hi | Bpk-lo], Bpk(M) = Apk(M^T).

typedef unsigned short u16;
typedef unsigned int u32;
typedef __bf16 bf16x8 __attribute__((ext_vector_type(8)));
typedef float f32x4 __attribute__((ext_vector_type(4)));
typedef u16 u16x4 __attribute__((ext_vector_type(4)));
typedef u16 u16x8 __attribute__((ext_vector_type(8)));

#define MAT 262144
#define SLOT 1048576
#define WSLOT 131072
#define P0 (17 * WSLOT) /* u16 offset of power-slot region in ws */

__device__ __forceinline__ u16 f2b(float f) {
  u32 x = __float_as_uint(f);
  return (u16)((x + 0x7fffu + ((x >> 16) & 1u)) >> 16);
}
__device__ __forceinline__ float b2f(u16 u) { return __uint_as_float(((u32)u) << 16); }

__device__ __forceinline__ size_t pidx(int r, int k) {
  return (size_t)(((r >> 4) * 16 + (k >> 5)) * 512 + ((k >> 3) & 3) * 128 + (r & 15) * 8 + (k & 7));
}

__device__ __forceinline__ void gll16(const void* g, void* l) {
  __builtin_amdgcn_global_load_lds((__attribute__((address_space(1))) void*)(void*)g,
                                   (__attribute__((address_space(3))) void*)l, 16, 0, 0);
}

__device__ __forceinline__ void grid_barrier(u32* bar) {
  __syncthreads();
  if (threadIdx.x == 0) {
    __threadfence();  // release: wb L2 so other XCDs can see this level's writes
    u32* cnt = bar;
    u32* gen = bar + 32;  // separate cache line
    u32 g = __hip_atomic_load(gen, __ATOMIC_RELAXED, __HIP_MEMORY_SCOPE_AGENT);
    u32 a = __hip_atomic_fetch_add(cnt, 1u, __ATOMIC_ACQ_REL, __HIP_MEMORY_SCOPE_AGENT);
    if (a == gridDim.x - 1) {
      __hip_atomic_store(cnt, 0u, __ATOMIC_RELAXED, __HIP_MEMORY_SCOPE_AGENT);
      __hip_atomic_store(gen, g + 1u, __ATOMIC_RELEASE, __HIP_MEMORY_SCOPE_AGENT);
    } else {
      while (__hip_atomic_load(gen, __ATOMIC_ACQUIRE, __HIP_MEMORY_SCOPE_AGENT) == g)
        __builtin_amdgcn_s_sleep(8);
    }
    __threadfence();  // acquire: invalidate L1/L2 before reading others' data
  }
  __syncthreads();
}

// ---- prep ----
__global__ __launch_bounds__(256) void prep_kernel(const float* __restrict__ Kc,
                                                   const float* __restrict__ z0,
                                                   u16* __restrict__ ws, u32* __restrict__ bar) {
  int tid = threadIdx.x, b = blockIdx.x;
  u16* P = ws + P0;
  if (b == 0 && tid == 0) { bar[0] = 0; bar[32] = 0; }
  if (b < 64) {
    int r0 = (b >> 3) * 64, c0b = (b & 7) * 64;
#pragma unroll
    for (int q = 0; q < 2; ++q) {
      int g = q * 256 + tid;
      int r = r0 + (g >> 3), c0 = c0b + (g & 7) * 8;
      float4 v0 = *(const float4*)(Kc + (size_t)r * 512 + c0);
      float4 v1 = *(const float4*)(Kc + (size_t)r * 512 + c0 + 4);
      float v[8] = {v0.x, v0.y, v0.z, v0.w, v1.x, v1.y, v1.z, v1.w};
      u16x8 h8, l8v;
#pragma unroll
      for (int j = 0; j < 8; ++j) {
        u16 h = f2b(v[j]);
        h8[j] = h;
        l8v[j] = f2b(v[j] - b2f(h));
        size_t ib = pidx(c0 + j, r);
        P[2 * MAT + ib] = h;
        P[3 * MAT + ib] = l8v[j];
      }
      size_t ia = pidx(r, c0);
      *(u16x8*)(P + ia) = h8;
      *(u16x8*)(P + MAT + ia) = l8v;
    }
  } else {
    int idb = b - 64;
    u16* W0 = ws;
    u16* z0lo = ws + 16 * WSLOT;
#pragma unroll
    for (int q = 0; q < 4; ++q) {
      int g = (idb * 4 + q) * 256 + tid;
      int r = g >> 6, c0 = (g & 63) * 8;
      float4 v0 = *(const float4*)(z0 + (size_t)r * 512 + c0);
      float4 v1 = *(const float4*)(z0 + (size_t)r * 512 + c0 + 4);
      float v[8] = {v0.x, v0.y, v0.z, v0.w, v1.x, v1.y, v1.z, v1.w};
      u16x8 h8, l8v;
#pragma unroll
      for (int j = 0; j < 8; ++j) {
        u16 h = f2b(v[j]);
        h8[j] = h;
        l8v[j] = f2b(v[j] - b2f(h));
      }
      size_t ia = pidx(r, c0);
      *(u16x8*)(W0 + ia) = h8;
      *(u16x8*)(z0lo + ia) = l8v;
    }
  }
}

// ---- fused ladder: 9 levels, grid barriers between. 64x32 tiles, bf16x3. ----
#define SL(s) (P0 + (s) * SLOT)
__global__ __launch_bounds__(256, 2) void ladder_kernel(u16* __restrict__ ws, u32* __restrict__ bar) {
  __shared__ u16 Bs[32768];
  // level tables: A hi/lo offset+stride, B-form offset+stride, C offset+stride, z, mtiles, wmode
  const int AH[9] = {SL(0), SL(0), SL(0), SL(0), SL(15), SL(15), SL(15), SL(15), 0};
  const int AL[9] = {SL(0) + MAT, SL(0) + MAT, SL(0) + MAT, SL(0) + MAT,
                     SL(15) + MAT, SL(15) + MAT, SL(15) + MAT, SL(15) + MAT, 16 * WSLOT};
  const int ASTR[9] = {0, SLOT, SLOT, SLOT, 0, SLOT, SLOT, SLOT, 0};
  const int BH[9] = {SL(0) + 2 * MAT, SL(1) + 2 * MAT, SL(3) + 2 * MAT, SL(7) + 2 * MAT,
                     SL(15) + 2 * MAT, SL(16) + 2 * MAT, SL(18) + 2 * MAT, SL(22) + 2 * MAT,
                     SL(15) + 2 * MAT};
  const int BSTR[9] = {0, 0, 0, 0, 0, 0, 0, 0, SLOT};
  const int CO[9] = {SL(1), SL(2), SL(4), SL(8), SL(16), SL(17), SL(19), SL(23), WSLOT};
  const int CSTR[9] = {0, SLOT, SLOT, SLOT, 0, SLOT, SLOT, SLOT, WSLOT};
  const int ZC[9] = {1, 2, 4, 8, 1, 2, 4, 7, 15};
  const int MTC[9] = {8, 8, 8, 8, 8, 8, 8, 8, 4};
  int wg = blockIdx.x, tid = threadIdx.x;
  int vw = ((wg & 7) << 5) | (wg >> 3);  // XCD-contiguous tile ranges
  int wv = tid >> 6, lane = tid & 63;
  int mrow = lane & 15, quad = lane >> 4, l8 = lane * 8;
  long prevKey = -1;
  for (int L = 0; L < 9; ++L) {
    int z = ZC[L], mt = MTC[L], wm = (L == 8);
    int T = z * mt * 16;
    int per = (T + 255) >> 8;
    int t0 = vw * per, t1 = t0 + per;
    if (t1 > T) t1 = T;
    for (int t = t0; t < t1; ++t) {
      int n = t / (z * mt);
      int rem = t - n * (z * mt);
      int zi = rem / mt, m = rem - zi * mt;
      const u16* Bh = ws + BH[L] + (long)zi * BSTR[L];
      const u16* ph = Bh + (long)n * 16384;  // 2 nchunks x 16 kchunks panel
      long key = (long)(ph - ws) + ((long)L << 40);
      if (key != prevKey) {
        __syncthreads();
        const u16* pl = ph + MAT;
#pragma unroll
        for (int i = 0; i < 8; ++i) {
          int ch = wv * 8 + i;
          gll16(ph + (long)ch * 512 + l8, Bs + ch * 512);
          gll16(pl + (long)ch * 512 + l8, Bs + 16384 + ch * 512);
        }
        __syncthreads();
        prevKey = key;
      }
      const u16* Ah = ws + AH[L] + (long)zi * ASTR[L];
      const u16* Al = ws + AL[L] + (long)zi * ASTR[L];
      u16* C = ws + CO[L] + (long)zi * CSTR[L];
      int m0 = m * 64, n0 = n * 32;
      int mc = (m0 >> 4) + wv;
      f32x4 acc[2] = {};
#pragma unroll 4
      for (int kt = 0; kt < 16; ++kt) {
        long co = (long)(mc * 16 + kt) * 512 + l8;
        bf16x8 ah = *(const bf16x8*)(Ah + co);
        bf16x8 al = *(const bf16x8*)(Al + co);
#pragma unroll
        for (int nt = 0; nt < 2; ++nt) {
          bf16x8 bh = *(const bf16x8*)(Bs + (nt * 16 + kt) * 512 + l8);
          bf16x8 bl = *(const bf16x8*)(Bs + 16384 + (nt * 16 + kt) * 512 + l8);
          acc[nt] = __builtin_amdgcn_mfma_f32_16x16x32_bf16(ah, bh, acc[nt], 0, 0, 0);
          acc[nt] = __builtin_amdgcn_mfma_f32_16x16x32_bf16(al, bh, acc[nt], 0, 0, 0);
          acc[nt] = __builtin_amdgcn_mfma_f32_16x16x32_bf16(ah, bl, acc[nt], 0, 0, 0);
        }
      }
      int mbase = m0 + wv * 16 + quad * 4;
#pragma unroll
      for (int nt = 0; nt < 2; ++nt) {
        int nn = n0 + nt * 16 + mrow;
        if (!wm) {
          u16x4 h4, l4;
#pragma unroll
          for (int r = 0; r < 4; ++r) {
            float v = acc[nt][r];
            u16 h = f2b(v), l = f2b(v - b2f(h));
            size_t ia = pidx(mbase + r, nn);
            C[ia] = h;
            C[MAT + ia] = l;
            h4[r] = h;
            l4[r] = l;
          }
          size_t ib = pidx(nn, mbase);
          *(u16x4*)(C + 2 * MAT + ib) = h4;
          *(u16x4*)(C + 3 * MAT + ib) = l4;
        } else {
#pragma unroll
          for (int r = 0; r < 4; ++r) C[pidx(mbase + r, nn)] = f2b(acc[nt][r]);
        }
      }
    }
    if (L < 8) grid_barrier(bar);
  }
}

// ---- parallel phase: out[:, 16j+i, :] = W_j @ K^{i+1}, plain bf16, 256x64 tile.
// blockIdx.x decode keeps each XCD on 4 B-forms + 8 W-slots (fits 4MB L2).
__global__ __launch_bounds__(256, 2) void gemm_out(const u16* __restrict__ Wb,
                                                   const u16* __restrict__ PT0,
                                                   float* __restrict__ out) {
  __shared__ u16 Bs[32768];
  int zz = blockIdx.x;
  int i = (zz & 3) | (((zz >> 3) & 3) << 2);
  int j = ((zz >> 2) & 1) | (((zz >> 5) & 7) << 1);
  int n0 = (zz >> 8) * 64;
  int t = j * 16 + i;
  const u16* A = Wb + (size_t)j * WSLOT;
  const u16* Bt = PT0 + (size_t)i * SLOT;
  int tid = threadIdx.x;
  int wv = tid >> 6, lane = tid & 63;
  int mrow = lane & 15, quad = lane >> 4, l8 = lane * 8;
  const u16* pb = Bt + (size_t)(n0 >> 4) * 16 * 512;
#pragma unroll
  for (int q = 0; q < 16; ++q) {
    int ch = wv * 16 + q;
    gll16(pb + (size_t)ch * 512 + l8, Bs + ch * 512);
  }
  __syncthreads();
  int mc0 = wv * 4;
  f32x4 acc[4][4] = {};
#pragma unroll 4
  for (int kt = 0; kt < 16; ++kt) {
    bf16x8 a[4], b[4];
#pragma unroll
    for (int mt = 0; mt < 4; ++mt)
      a[mt] = *(const bf16x8*)(A + (size_t)((mc0 + mt) * 16 + kt) * 512 + l8);
#pragma unroll
    for (int nt = 0; nt < 4; ++nt)
      b[nt] = *(const bf16x8*)(Bs + (nt * 16 + kt) * 512 + l8);
#pragma unroll
    for (int mt = 0; mt < 4; ++mt)
#pragma unroll
      for (int nt = 0; nt < 4; ++nt)
        acc[mt][nt] = __builtin_amdgcn_mfma_f32_16x16x32_bf16(a[mt], b[nt], acc[mt][nt], 0, 0, 0);
  }
#pragma unroll
  for (int mt = 0; mt < 4; ++mt)
#pragma unroll
    for (int nt = 0; nt < 4; ++nt) {
      int gb = wv * 64 + mt * 16 + quad * 4;
      int gd = n0 + nt * 16 + mrow;
#pragma unroll
      for (int r = 0; r < 4; ++r)
        out[((size_t)(gb + r) * 256 + t) * 512 + gd] = acc[mt][nt][r];
    }
}

extern "C" void kernel_launch(void* const* d_in, const int* in_sizes, int n_in,
                              void* d_out, int out_size, void* d_ws, size_t ws_size,
                              hipStream_t stream) {
  const float* z0 = (const float*)d_in[0];
  const float* Kc = (const float*)d_in[1];
  float* out = (float*)d_out;
  // ws (u16): W[16*WSLOT] | z0lo[WSLOT] | P[30*SLOT] | barrier (2 cache lines)
  u16* ws = (u16*)d_ws;
  u32* bar = (u32*)(ws + (size_t)P0 + 30 * (size_t)SLOT);
  dim3 blk(256);
  prep_kernel<<<80, blk, 0, stream>>>(Kc, z0, ws, bar);
  ladder_kernel<<<256, blk, 0, stream>>>(ws, bar);
  gemm_out<<<2048, blk, 0, stream>>>(ws, ws + P0 + 2 * MAT, out);
}